// Round 1
// baseline (1180.833 us; speedup 1.0000x reference)
//
#include <hip/hip_runtime.h>
#include <hip/hip_cooperative_groups.h>

namespace cg = cooperative_groups;

#define BATCH 32
#define HID   128
#define EMB   64
#define DEPTHS 32
#define NODES 512
#define PAR   8
#define OUTROWS 16385                 // 1 + D*N  (slot s of ref buf -> out row s-1)
#define ROWSTRIDE ((size_t)OUTROWS * HID)

typedef short bf16x8 __attribute__((ext_vector_type(8)));
typedef float f32x4  __attribute__((ext_vector_type(4)));

// ws layout (ushort elements): W1h[24576] | W1l[24576] | W2h[16384] | W2l[16384]
#define WS_W1L 24576
#define WS_W2H 49152
#define WS_W2L 65536
#define WS_BYTES 163840

// x = hi + lo, both bf16 (truncation split: combined rel err ~2^-17)
__device__ __forceinline__ void split1(float x, unsigned short& h, unsigned short& l) {
    unsigned u  = __float_as_uint(x);
    unsigned hu = u & 0xFFFF0000u;
    h = (unsigned short)(hu >> 16);
    float r = x - __uint_as_float(hu);
    l = (unsigned short)(__float_as_uint(r) >> 16);
}

// out[b][0][:] = embedding[b][:]   (root, slot 1)
__global__ void __launch_bounds__(256) init_kernel(const float* __restrict__ emb,
                                                   float* __restrict__ out) {
    int i = blockIdx.x * 256 + threadIdx.x;      // 0..4095
    int b = i >> 7, h = i & 127;
    out[(size_t)b * ROWSTRIDE + h] = emb[i];
}

// split W1,W2 into bf16 hi/lo in ws (runs every launch; ws is re-poisoned)
__global__ void __launch_bounds__(256) prep_kernel(const float* __restrict__ W1f,
                                                   const float* __restrict__ W2f,
                                                   unsigned short* __restrict__ wsw) {
    int i = blockIdx.x * 256 + threadIdx.x;      // 0..40959
    unsigned short h, l;
    if (i < 24576) {
        split1(W1f[i], h, l);
        wsw[i] = h; wsw[WS_W1L + i] = l;
    } else {
        int j = i - 24576;                        // 0..16383
        split1(W2f[j], h, l);
        wsw[WS_W2H + j] = h; wsw[WS_W2L + j] = l;
    }
}

// One depth step for one 16-node tile of one batch. 256 threads = 4 waves.
// LDS strides: xs 204 f32 (16B-aligned rows); xh/xl 216 u16 (432B rows, 2-way banks);
// hh/hl 136 u16 (272B rows, 2-way banks); os 132 f32.
__device__ __forceinline__ void depth_body(
    char* smem,
    float* __restrict__ bbase,               // buf + b*ROWSTRIDE
    const float* __restrict__ emb_table,     // [16386][64]
    const float* __restrict__ W1f,           // [128][192]
    const float* __restrict__ b1,            // [128]
    const float* __restrict__ W2f,           // [128][128]
    const float* __restrict__ b2,            // [128]
    const int*   __restrict__ parent_idx,    // [32][512][8]
    const unsigned short* __restrict__ wsw,  // split weights (if use_ws)
    int d, int n0, int use_ws, int t)
{
    float* xs = (float*)smem;                       // [16][204]: 0..127 pv, 128..191 emb

    // ---------- gather pv + node embedding into xs ----------
    {
        const int lane = t & 31, rsub = t >> 5;     // 32 lanes per row
        for (int rr = rsub; rr < 16; rr += 8) {
            const int* pp = parent_idx + ((d << 9) + n0 + rr) * PAR;
            float4 a = make_float4(0.f, 0.f, 0.f, 0.f);
            #pragma unroll
            for (int p = 0; p < PAR; ++p) {
                const int s = pp[p];
                if (s > 0) {
                    const float4 v = *(const float4*)(bbase + (size_t)(s - 1) * HID + lane * 4);
                    a.x += v.x; a.y += v.y; a.z += v.z; a.w += v.w;
                }
            }
            *(float4*)&xs[rr * 204 + lane * 4] = a;
        }
        const int base_row = 2 + (d << 9) + n0;
        const int r = t >> 4, e4 = t & 15;
        *(float4*)&xs[r * 204 + 128 + e4 * 4] =
            *(const float4*)(emb_table + (size_t)(base_row + r) * EMB + e4 * 4);
    }
    __syncthreads();

    // ---------- split x -> bf16 hi/lo (once per element) ----------
    unsigned short* xh = (unsigned short*)(smem + 13056);
    unsigned short* xl = xh + 16 * 216;
    {
        const int r = t >> 4, cs = (t & 15) * 12;   // 16 threads/row x 12 cols = 192
        #pragma unroll
        for (int j = 0; j < 12; ++j) {
            unsigned short h, l;
            split1(xs[r * 204 + cs + j], h, l);
            xh[r * 216 + cs + j] = h;
            xl[r * 216 + cs + j] = l;
        }
    }
    __syncthreads();

    const int lane = t & 63, w = t >> 6;
    const int quad = lane >> 4, nib = lane & 15;

    // ---------- GEMM1: h = x[16x192] @ W1^T via MFMA ----------
    f32x4 acc1[2] = {{0.f,0.f,0.f,0.f},{0.f,0.f,0.f,0.f}};
    for (int k0 = 0; k0 < 192; k0 += 32) {
        const int ko = k0 + quad * 8;
        const bf16x8 ah = *(const bf16x8*)(xh + nib * 216 + ko);
        const bf16x8 al = *(const bf16x8*)(xl + nib * 216 + ko);
        #pragma unroll
        for (int nt = 0; nt < 2; ++nt) {
            const int n = ((w << 1) + nt) * 16 + nib;
            bf16x8 bh, bl;
            if (use_ws) {
                bh = *(const bf16x8*)(wsw + n * 192 + ko);
                bl = *(const bf16x8*)(wsw + WS_W1L + n * 192 + ko);
            } else {
                const float4 f0 = *(const float4*)(W1f + n * 192 + ko);
                const float4 f1 = *(const float4*)(W1f + n * 192 + ko + 4);
                const float ff[8] = {f0.x,f0.y,f0.z,f0.w,f1.x,f1.y,f1.z,f1.w};
                #pragma unroll
                for (int j = 0; j < 8; ++j) {
                    unsigned short hq, lq; split1(ff[j], hq, lq);
                    bh[j] = (short)hq; bl[j] = (short)lq;
                }
            }
            acc1[nt] = __builtin_amdgcn_mfma_f32_16x16x32_bf16(ah, bh, acc1[nt], 0, 0, 0);
            acc1[nt] = __builtin_amdgcn_mfma_f32_16x16x32_bf16(ah, bl, acc1[nt], 0, 0, 0);
            acc1[nt] = __builtin_amdgcn_mfma_f32_16x16x32_bf16(al, bh, acc1[nt], 0, 0, 0);
        }
    }
    __syncthreads();   // all waves done reading xh/xl before aliasing with hh/hl

    // ---------- epilogue 1: bias+relu, split -> hh/hl ----------
    unsigned short* hh = (unsigned short*)(smem + 13056);
    unsigned short* hl = hh + 16 * 136;
    #pragma unroll
    for (int nt = 0; nt < 2; ++nt) {
        const int c = ((w << 1) + nt) * 16 + nib;
        const float bb = b1[c];
        #pragma unroll
        for (int reg = 0; reg < 4; ++reg) {
            const int r = quad * 4 + reg;
            float h = fmaxf(acc1[nt][reg] + bb, 0.f);
            unsigned short hq, lq; split1(h, hq, lq);
            hh[r * 136 + c] = hq;
            hl[r * 136 + c] = lq;
        }
    }
    __syncthreads();

    // ---------- GEMM2: h2 = h[16x128] @ W2^T via MFMA ----------
    f32x4 acc2[2] = {{0.f,0.f,0.f,0.f},{0.f,0.f,0.f,0.f}};
    for (int k0 = 0; k0 < 128; k0 += 32) {
        const int ko = k0 + quad * 8;
        const bf16x8 ah = *(const bf16x8*)(hh + nib * 136 + ko);
        const bf16x8 al = *(const bf16x8*)(hl + nib * 136 + ko);
        #pragma unroll
        for (int nt = 0; nt < 2; ++nt) {
            const int n = ((w << 1) + nt) * 16 + nib;
            bf16x8 bh, bl;
            if (use_ws) {
                bh = *(const bf16x8*)(wsw + WS_W2H + n * 128 + ko);
                bl = *(const bf16x8*)(wsw + WS_W2L + n * 128 + ko);
            } else {
                const float4 f0 = *(const float4*)(W2f + n * 128 + ko);
                const float4 f1 = *(const float4*)(W2f + n * 128 + ko + 4);
                const float ff[8] = {f0.x,f0.y,f0.z,f0.w,f1.x,f1.y,f1.z,f1.w};
                #pragma unroll
                for (int j = 0; j < 8; ++j) {
                    unsigned short hq, lq; split1(ff[j], hq, lq);
                    bh[j] = (short)hq; bl[j] = (short)lq;
                }
            }
            acc2[nt] = __builtin_amdgcn_mfma_f32_16x16x32_bf16(ah, bh, acc2[nt], 0, 0, 0);
            acc2[nt] = __builtin_amdgcn_mfma_f32_16x16x32_bf16(ah, bl, acc2[nt], 0, 0, 0);
            acc2[nt] = __builtin_amdgcn_mfma_f32_16x16x32_bf16(al, bh, acc2[nt], 0, 0, 0);
        }
    }
    __syncthreads();   // all waves done reading hh/hl before aliasing with os

    // ---------- epilogue 2: os = h2 + b2 ----------
    float* os = (float*)(smem + 13056);             // [16][132]
    #pragma unroll
    for (int nt = 0; nt < 2; ++nt) {
        const int c = ((w << 1) + nt) * 16 + nib;
        const float bb = b2[c];
        #pragma unroll
        for (int reg = 0; reg < 4; ++reg) {
            const int r = quad * 4 + reg;
            os[r * 132 + c] = acc2[nt][reg] + bb;
        }
    }
    __syncthreads();

    // ---------- merged store: v = pv + os, coalesced float4 ----------
    {
        const int r = t >> 4, c = (t & 15) * 8;
        float4 o0 = *(float4*)&os[r * 132 + c];
        float4 o1 = *(float4*)&os[r * 132 + c + 4];
        const float4 p0 = *(const float4*)&xs[r * 204 + c];
        const float4 p1 = *(const float4*)&xs[r * 204 + c + 4];
        o0.x += p0.x; o0.y += p0.y; o0.z += p0.z; o0.w += p0.w;
        o1.x += p1.x; o1.y += p1.y; o1.z += p1.z; o1.w += p1.w;
        float* dst = bbase + (size_t)(1 + (d << 9) + n0 + r) * HID + c;
        *(float4*)dst = o0;
        *(float4*)(dst + 4) = o1;
    }
}

// XCD-chunked bijective swizzle: blocks with bid%8==k land on XCD k; give XCD k
// a contiguous chunk of (batch, tile) work so its L2 sees only 4 batches' rows.
__device__ __forceinline__ int swizzle_wg(int bid) {
    return ((bid & 7) << 7) + (bid >> 3);           // 1024 % 8 == 0 -> bijective
}

// Fallback: one depth per launch (verified baseline path).
__global__ void __launch_bounds__(256) depth_kernel(
    float* __restrict__ buf, const float* __restrict__ emb_table,
    const float* __restrict__ W1f, const float* __restrict__ b1,
    const float* __restrict__ W2f, const float* __restrict__ b2,
    const int* __restrict__ parent_idx, const unsigned short* __restrict__ wsw,
    int d, int use_ws)
{
    __shared__ __align__(16) char smem[13056 + 13824];
    const int swz = swizzle_wg(blockIdx.x);
    const int b   = swz >> 5;
    const int n0  = (swz & 31) << 4;
    float* __restrict__ bbase = buf + (size_t)b * ROWSTRIDE;
    depth_body(smem, bbase, emb_table, W1f, b1, W2f, b2, parent_idx, wsw,
               d, n0, use_ws, threadIdx.x);
}

// Persistent cooperative kernel: all 32 depths, grid.sync() between them.
// 4 blocks/CU guaranteed by launch bounds (LDS 26.9KB*4=107KB <= 160KB, VGPR<=128).
__global__ void __launch_bounds__(256, 4) depth_all_kernel(
    float* __restrict__ buf, const float* __restrict__ emb_table,
    const float* __restrict__ W1f, const float* __restrict__ b1,
    const float* __restrict__ W2f, const float* __restrict__ b2,
    const int* __restrict__ parent_idx, const unsigned short* __restrict__ wsw,
    int use_ws)
{
    cg::grid_group grid = cg::this_grid();
    __shared__ __align__(16) char smem[13056 + 13824];
    const int t   = threadIdx.x;
    const int swz = swizzle_wg(blockIdx.x);
    const int b   = swz >> 5;
    const int n0  = (swz & 31) << 4;
    float* __restrict__ bbase = buf + (size_t)b * ROWSTRIDE;

    for (int d = 0; d < DEPTHS; ++d) {
        if (d) grid.sync();   // depth d may read any earlier depth's rows
        depth_body(smem, bbase, emb_table, W1f, b1, W2f, b2, parent_idx, wsw,
                   d, n0, use_ws, t);
    }
}

extern "C" void kernel_launch(void* const* d_in, const int* in_sizes, int n_in,
                              void* d_out, int out_size, void* d_ws, size_t ws_size,
                              hipStream_t stream) {
    const float* embedding  = (const float*)d_in[0];
    const float* emb_table  = (const float*)d_in[1];
    const float* W1         = (const float*)d_in[2];
    const float* b1         = (const float*)d_in[3];
    const float* W2         = (const float*)d_in[4];
    const float* b2         = (const float*)d_in[5];
    const int*   parent_idx = (const int*)d_in[6];
    float* out = (float*)d_out;
    unsigned short* wsw = (unsigned short*)d_ws;
    int use_ws = (ws_size >= (size_t)WS_BYTES) ? 1 : 0;

    init_kernel<<<16, 256, 0, stream>>>(embedding, out);
    if (use_ws) prep_kernel<<<160, 256, 0, stream>>>(W1, W2, wsw);

    // One-time host-side capacity check for the cooperative path (no stream ops).
    static int coop_ok = -1;
    if (coop_ok < 0) {
        int nb = 0;
        hipError_t e = hipOccupancyMaxActiveBlocksPerMultiprocessor(
            &nb, depth_all_kernel, 256, 0);
        coop_ok = (e == hipSuccess && nb >= 4) ? 1 : 0;   // need 1024 = 4 * 256CU
    }

    bool launched = false;
    if (coop_ok) {
        void* args[] = {(void*)&out, (void*)&emb_table, (void*)&W1, (void*)&b1,
                        (void*)&W2, (void*)&b2, (void*)&parent_idx, (void*)&wsw,
                        (void*)&use_ws};
        hipError_t e = hipLaunchCooperativeKernel(
            (const void*)depth_all_kernel, dim3(1024), dim3(256), args, 0, stream);
        launched = (e == hipSuccess);
        if (!launched) coop_ok = 0;   // don't retry the broken path
    }
    if (!launched) {
        for (int d = 0; d < DEPTHS; ++d) {
            depth_kernel<<<1024, 256, 0, stream>>>(out, emb_table, W1, b1, W2, b2,
                                                   parent_idx, wsw, d, use_ws);
        }
    }
}

// Round 2
// 1073.896 us; speedup vs baseline: 1.0996x; 1.0996x over previous
//
#include <hip/hip_runtime.h>

#define BATCH 32
#define HID   128
#define EMB   64
#define DEPTHS 32
#define NODES 512
#define PAR   8
#define OUTROWS 16385                 // 1 + D*N  (slot s of ref buf -> out row s-1)
#define ROWSTRIDE ((size_t)OUTROWS * HID)
#define TOTALSLOTS 16386

typedef short bf16x8 __attribute__((ext_vector_type(8)));
typedef float f32x4  __attribute__((ext_vector_type(4)));

// ---- old-path ws layout (ushort units) ----
#define WS_W1L 24576
#define WS_W2H 49152
#define WS_W2L 65536
#define WS_BYTES 163840

// ---- fast-path ws layout (byte offsets) ----
// W1a = W1[:, 0:128] split planes, W2 split planes, E' = emb@W1b^T + b1, WB = [slot][batch][H] f32
#define FW_W1AH 0u
#define FW_W1AL 32768u
#define FW_W2H  65536u
#define FW_W2L  98304u
#define FW_EP   131072u                                   // f32[16384*128] = 8 MB
#define FW_WB   (131072u + 8388608u)                      // f32[16386*32*128] = 268.4 MB
#define FW_BYTES ((size_t)FW_WB + (size_t)TOTALSLOTS * BATCH * HID * 4)

// x = hi + lo, both bf16 (truncation split: combined rel err ~2^-17)
__device__ __forceinline__ void split1(float x, unsigned short& h, unsigned short& l) {
    unsigned u  = __float_as_uint(x);
    unsigned hu = u & 0xFFFF0000u;
    h = (unsigned short)(hu >> 16);
    float r = x - __uint_as_float(hu);
    l = (unsigned short)(__float_as_uint(r) >> 16);
}

// ============================ FAST PATH ============================

// out[b][0][:] = embedding ; WB[slot=1][b][:] = embedding
__global__ void __launch_bounds__(256) init_fast_kernel(const float* __restrict__ emb,
                                                        float* __restrict__ out,
                                                        float* __restrict__ wb) {
    int i = blockIdx.x * 256 + threadIdx.x;      // 0..4095
    int b = i >> 7, h = i & 127;
    float v = emb[i];
    out[(size_t)b * ROWSTRIDE + h] = v;
    wb[(size_t)(BATCH + b) * HID + h] = v;       // slot 1 rows: 32..63
}

// split W1a (=W1[:, :128]) and W2 into bf16 hi/lo planes
__global__ void __launch_bounds__(256) prep_w_fast(const float* __restrict__ W1f,
                                                   const float* __restrict__ W2f,
                                                   char* __restrict__ ws) {
    int i = blockIdx.x * 256 + threadIdx.x;      // 0..16383
    unsigned short h, l;
    split1(W1f[(i >> 7) * 192 + (i & 127)], h, l);
    ((unsigned short*)(ws + FW_W1AH))[i] = h;
    ((unsigned short*)(ws + FW_W1AL))[i] = l;
    split1(W2f[i], h, l);
    ((unsigned short*)(ws + FW_W2H))[i] = h;
    ((unsigned short*)(ws + FW_W2L))[i] = l;
}

// E'[i][c] = b1[c] + sum_e emb_table[2+i][e] * W1[c][128+e]   (f32, exact-ish)
__global__ void __launch_bounds__(256) prep_e_fast(const float* __restrict__ emb_table,
                                                   const float* __restrict__ W1f,
                                                   const float* __restrict__ b1,
                                                   float* __restrict__ ep) {
    __shared__ float semb[16 * 64];              // 16 node-emb rows
    __shared__ float swT[64 * 129];              // W1b transposed, padded (bank-safe)
    const int t  = threadIdx.x;
    const int nb = blockIdx.x * 16;              // first global node index i
    ((float4*)semb)[t] = ((const float4*)(emb_table + (size_t)(2 + nb) * EMB))[t];
    for (int q = t; q < 8192; q += 256) {        // coalesced read, swizzle-free write
        const int c = q >> 6, e = q & 63;        // 64-lane groups: c uniform, e 0..63
        swT[e * 129 + c] = W1f[c * 192 + 128 + e];
    }
    __syncthreads();
    #pragma unroll
    for (int u = 0; u < 8; ++u) {
        const int q = t + 256 * u;               // 0..2047
        const int r = q >> 7, c = q & 127;
        float acc = b1[c];
        #pragma unroll 4
        for (int e = 0; e < 64; ++e)
            acc += semb[r * 64 + e] * swT[e * 129 + c];
        ep[(size_t)(nb + r) * HID + c] = acc;
    }
}

// One (node, batch-half) tile. 256 threads = 4 waves. All parent reads are
// contiguous 8 KB streams from WB[slot][batch][H].
__global__ void __launch_bounds__(256, 4) depth_fast_kernel(
    float* __restrict__ out,
    const int* __restrict__ parent_idx,
    const float* __restrict__ b2,
    char* __restrict__ ws, int d)
{
    __shared__ __align__(16) char smem[8448 + 8704];
    float* xs = (float*)smem;                    // pv [16][132] f32

    const int t   = threadIdx.x;
    const int bid = blockIdx.x;
    const int swz = ((bid & 7) << 7) + (bid >> 3);   // XCD-chunked, bijective (1024%8==0)
    const int n   = swz >> 1;                        // node 0..511
    const int bo  = (swz & 1) << 4;                  // batch offset 0 / 16
    float* __restrict__ wb = (float*)(ws + FW_WB);

    // ---------- gather: sum 8 parent slots, each a contiguous [16][128] chunk ----------
    {
        const int q = (((d << 9) + n) << 3);
        const int4 pa = *(const int4*)(parent_idx + q);
        const int4 pb = *(const int4*)(parent_idx + q + 4);
        const int sarr[8] = {pa.x, pa.y, pa.z, pa.w, pb.x, pb.y, pb.z, pb.w};
        f32x4 a0 = {0.f,0.f,0.f,0.f}, a1 = {0.f,0.f,0.f,0.f};
        #pragma unroll
        for (int p = 0; p < PAR; ++p) {
            const int s = sarr[p];                   // uniform across block
            if (s > 0) {
                const float* base = wb + ((size_t)s * BATCH + bo) * HID;
                const f32x4 v0 = *(const f32x4*)(base + (t << 2));
                const f32x4 v1 = *(const f32x4*)(base + 1024 + (t << 2));
                a0 += v0; a1 += v1;
            }
        }
        const int r0 = t >> 5, c0 = (t & 31) << 2;
        *(f32x4*)&xs[r0 * 132 + c0]       = a0;
        *(f32x4*)&xs[(r0 + 8) * 132 + c0] = a1;
    }
    __syncthreads();

    // ---------- split pv -> bf16 hi/lo ----------
    unsigned short* xh = (unsigned short*)(smem + 8448);
    unsigned short* xl = xh + 16 * 136;
    {
        const int r = t >> 4, cs = (t & 15) << 3;
        #pragma unroll
        for (int j = 0; j < 8; ++j) {
            unsigned short h, l;
            split1(xs[r * 132 + cs + j], h, l);
            xh[r * 136 + cs + j] = h;
            xl[r * 136 + cs + j] = l;
        }
    }
    __syncthreads();

    const int lane = t & 63, w = t >> 6;
    const int quad = lane >> 4, nib = lane & 15;

    // ---------- GEMM1: h = pv[16x128] @ W1a^T ----------
    const unsigned short* w1h = (const unsigned short*)(ws + FW_W1AH);
    const unsigned short* w1l = (const unsigned short*)(ws + FW_W1AL);
    f32x4 acc1[2] = {{0.f,0.f,0.f,0.f},{0.f,0.f,0.f,0.f}};
    for (int k0 = 0; k0 < 128; k0 += 32) {
        const int ko = k0 + quad * 8;
        const bf16x8 ah = *(const bf16x8*)(xh + nib * 136 + ko);
        const bf16x8 al = *(const bf16x8*)(xl + nib * 136 + ko);
        #pragma unroll
        for (int nt = 0; nt < 2; ++nt) {
            const int c = ((w << 1) + nt) * 16 + nib;
            const bf16x8 bh = *(const bf16x8*)(w1h + c * 128 + ko);
            const bf16x8 bl = *(const bf16x8*)(w1l + c * 128 + ko);
            acc1[nt] = __builtin_amdgcn_mfma_f32_16x16x32_bf16(ah, bh, acc1[nt], 0, 0, 0);
            acc1[nt] = __builtin_amdgcn_mfma_f32_16x16x32_bf16(ah, bl, acc1[nt], 0, 0, 0);
            acc1[nt] = __builtin_amdgcn_mfma_f32_16x16x32_bf16(al, bh, acc1[nt], 0, 0, 0);
        }
    }
    __syncthreads();

    // ---------- epilogue 1: bias (E' includes emb-part + b1) + relu, split ----------
    unsigned short* hh = xh;                      // alias (safe after barrier)
    unsigned short* hl = xl;
    const float* __restrict__ epn = (const float*)(ws + FW_EP) + (size_t)((d << 9) + n) * HID;
    #pragma unroll
    for (int nt = 0; nt < 2; ++nt) {
        const int c = ((w << 1) + nt) * 16 + nib;
        const float bb = epn[c];
        #pragma unroll
        for (int reg = 0; reg < 4; ++reg) {
            const int r = quad * 4 + reg;
            float h = fmaxf(acc1[nt][reg] + bb, 0.f);
            unsigned short hq, lq; split1(h, hq, lq);
            hh[r * 136 + c] = hq;
            hl[r * 136 + c] = lq;
        }
    }
    __syncthreads();

    // ---------- GEMM2: h2 = h[16x128] @ W2^T ----------
    const unsigned short* w2h = (const unsigned short*)(ws + FW_W2H);
    const unsigned short* w2l = (const unsigned short*)(ws + FW_W2L);
    f32x4 acc2[2] = {{0.f,0.f,0.f,0.f},{0.f,0.f,0.f,0.f}};
    for (int k0 = 0; k0 < 128; k0 += 32) {
        const int ko = k0 + quad * 8;
        const bf16x8 ah = *(const bf16x8*)(hh + nib * 136 + ko);
        const bf16x8 al = *(const bf16x8*)(hl + nib * 136 + ko);
        #pragma unroll
        for (int nt = 0; nt < 2; ++nt) {
            const int c = ((w << 1) + nt) * 16 + nib;
            const bf16x8 bh = *(const bf16x8*)(w2h + c * 128 + ko);
            const bf16x8 bl = *(const bf16x8*)(w2l + c * 128 + ko);
            acc2[nt] = __builtin_amdgcn_mfma_f32_16x16x32_bf16(ah, bh, acc2[nt], 0, 0, 0);
            acc2[nt] = __builtin_amdgcn_mfma_f32_16x16x32_bf16(ah, bl, acc2[nt], 0, 0, 0);
            acc2[nt] = __builtin_amdgcn_mfma_f32_16x16x32_bf16(al, bh, acc2[nt], 0, 0, 0);
        }
    }
    __syncthreads();

    // ---------- epilogue 2: os = h2 + b2 ----------
    float* os = (float*)(smem + 8448);           // alias hh/hl (safe after barrier)
    #pragma unroll
    for (int nt = 0; nt < 2; ++nt) {
        const int c = ((w << 1) + nt) * 16 + nib;
        const float bb = b2[c];
        #pragma unroll
        for (int reg = 0; reg < 4; ++reg) {
            const int r = quad * 4 + reg;
            os[r * 132 + c] = acc2[nt][reg] + bb;
        }
    }
    __syncthreads();

    // ---------- store v = pv + os: to WB (contiguous) and to out (per-batch rows) ----------
    {
        const int r = t >> 4, c = (t & 15) << 3;
        f32x4 o0 = *(f32x4*)&os[r * 132 + c];
        f32x4 o1 = *(f32x4*)&os[r * 132 + c + 4];
        o0 += *(const f32x4*)&xs[r * 132 + c];
        o1 += *(const f32x4*)&xs[r * 132 + c + 4];
        const size_t slot = (size_t)2 + (d << 9) + n;
        float* dwb = wb + (slot * BATCH + bo + r) * HID + c;
        *(f32x4*)dwb = o0;
        *(f32x4*)(dwb + 4) = o1;
        float* dou = out + (size_t)(bo + r) * ROWSTRIDE
                         + ((size_t)1 + (d << 9) + n) * HID + c;
        *(f32x4*)dou = o0;
        *(f32x4*)(dou + 4) = o1;
    }
}

// ============================ FALLBACK PATH (verified @1180) ============================

__global__ void __launch_bounds__(256) init_kernel(const float* __restrict__ emb,
                                                   float* __restrict__ out) {
    int i = blockIdx.x * 256 + threadIdx.x;
    int b = i >> 7, h = i & 127;
    out[(size_t)b * ROWSTRIDE + h] = emb[i];
}

__global__ void __launch_bounds__(256) prep_kernel(const float* __restrict__ W1f,
                                                   const float* __restrict__ W2f,
                                                   unsigned short* __restrict__ wsw) {
    int i = blockIdx.x * 256 + threadIdx.x;
    unsigned short h, l;
    if (i < 24576) {
        split1(W1f[i], h, l);
        wsw[i] = h; wsw[WS_W1L + i] = l;
    } else {
        int j = i - 24576;
        split1(W2f[j], h, l);
        wsw[WS_W2H + j] = h; wsw[WS_W2L + j] = l;
    }
}

__global__ void __launch_bounds__(256) depth_kernel(
    float* __restrict__ buf, const float* __restrict__ emb_table,
    const float* __restrict__ W1f, const float* __restrict__ b1,
    const float* __restrict__ W2f, const float* __restrict__ b2,
    const int* __restrict__ parent_idx, const unsigned short* __restrict__ wsw,
    int d, int use_ws)
{
    __shared__ __align__(16) char smem[13056 + 13824];
    float* xs = (float*)smem;
    const int t   = threadIdx.x;
    const int swz = ((blockIdx.x & 7) << 7) + (blockIdx.x >> 3);
    const int b   = swz >> 5;
    const int n0  = (swz & 31) << 4;
    float* __restrict__ bbase = buf + (size_t)b * ROWSTRIDE;

    {
        const int lane = t & 31, rsub = t >> 5;
        for (int rr = rsub; rr < 16; rr += 8) {
            const int* pp = parent_idx + ((d << 9) + n0 + rr) * PAR;
            float4 a = make_float4(0.f, 0.f, 0.f, 0.f);
            #pragma unroll
            for (int p = 0; p < PAR; ++p) {
                const int s = pp[p];
                if (s > 0) {
                    const float4 v = *(const float4*)(bbase + (size_t)(s - 1) * HID + lane * 4);
                    a.x += v.x; a.y += v.y; a.z += v.z; a.w += v.w;
                }
            }
            *(float4*)&xs[rr * 204 + lane * 4] = a;
        }
        const int base_row = 2 + (d << 9) + n0;
        const int r = t >> 4, e4 = t & 15;
        *(float4*)&xs[r * 204 + 128 + e4 * 4] =
            *(const float4*)(emb_table + (size_t)(base_row + r) * EMB + e4 * 4);
    }
    __syncthreads();

    unsigned short* xh = (unsigned short*)(smem + 13056);
    unsigned short* xl = xh + 16 * 216;
    {
        const int r = t >> 4, cs = (t & 15) * 12;
        #pragma unroll
        for (int j = 0; j < 12; ++j) {
            unsigned short h, l;
            split1(xs[r * 204 + cs + j], h, l);
            xh[r * 216 + cs + j] = h;
            xl[r * 216 + cs + j] = l;
        }
    }
    __syncthreads();

    const int lane = t & 63, w = t >> 6;
    const int quad = lane >> 4, nib = lane & 15;

    f32x4 acc1[2] = {{0.f,0.f,0.f,0.f},{0.f,0.f,0.f,0.f}};
    for (int k0 = 0; k0 < 192; k0 += 32) {
        const int ko = k0 + quad * 8;
        const bf16x8 ah = *(const bf16x8*)(xh + nib * 216 + ko);
        const bf16x8 al = *(const bf16x8*)(xl + nib * 216 + ko);
        #pragma unroll
        for (int nt = 0; nt < 2; ++nt) {
            const int n = ((w << 1) + nt) * 16 + nib;
            bf16x8 bh, bl;
            if (use_ws) {
                bh = *(const bf16x8*)(wsw + n * 192 + ko);
                bl = *(const bf16x8*)(wsw + WS_W1L + n * 192 + ko);
            } else {
                const float4 f0 = *(const float4*)(W1f + n * 192 + ko);
                const float4 f1 = *(const float4*)(W1f + n * 192 + ko + 4);
                const float ff[8] = {f0.x,f0.y,f0.z,f0.w,f1.x,f1.y,f1.z,f1.w};
                #pragma unroll
                for (int j = 0; j < 8; ++j) {
                    unsigned short hq, lq; split1(ff[j], hq, lq);
                    bh[j] = (short)hq; bl[j] = (short)lq;
                }
            }
            acc1[nt] = __builtin_amdgcn_mfma_f32_16x16x32_bf16(ah, bh, acc1[nt], 0, 0, 0);
            acc1[nt] = __builtin_amdgcn_mfma_f32_16x16x32_bf16(ah, bl, acc1[nt], 0, 0, 0);
            acc1[nt] = __builtin_amdgcn_mfma_f32_16x16x32_bf16(al, bh, acc1[nt], 0, 0, 0);
        }
    }
    __syncthreads();

    unsigned short* hh = (unsigned short*)(smem + 13056);
    unsigned short* hl = hh + 16 * 136;
    #pragma unroll
    for (int nt = 0; nt < 2; ++nt) {
        const int c = ((w << 1) + nt) * 16 + nib;
        const float bb = b1[c];
        #pragma unroll
        for (int reg = 0; reg < 4; ++reg) {
            const int r = quad * 4 + reg;
            float h = fmaxf(acc1[nt][reg] + bb, 0.f);
            unsigned short hq, lq; split1(h, hq, lq);
            hh[r * 136 + c] = hq;
            hl[r * 136 + c] = lq;
        }
    }
    __syncthreads();

    f32x4 acc2[2] = {{0.f,0.f,0.f,0.f},{0.f,0.f,0.f,0.f}};
    for (int k0 = 0; k0 < 128; k0 += 32) {
        const int ko = k0 + quad * 8;
        const bf16x8 ah = *(const bf16x8*)(hh + nib * 136 + ko);
        const bf16x8 al = *(const bf16x8*)(hl + nib * 136 + ko);
        #pragma unroll
        for (int nt = 0; nt < 2; ++nt) {
            const int n = ((w << 1) + nt) * 16 + nib;
            bf16x8 bh, bl;
            if (use_ws) {
                bh = *(const bf16x8*)(wsw + WS_W2H + n * 128 + ko);
                bl = *(const bf16x8*)(wsw + WS_W2L + n * 128 + ko);
            } else {
                const float4 f0 = *(const float4*)(W2f + n * 128 + ko);
                const float4 f1 = *(const float4*)(W2f + n * 128 + ko + 4);
                const float ff[8] = {f0.x,f0.y,f0.z,f0.w,f1.x,f1.y,f1.z,f1.w};
                #pragma unroll
                for (int j = 0; j < 8; ++j) {
                    unsigned short hq, lq; split1(ff[j], hq, lq);
                    bh[j] = (short)hq; bl[j] = (short)lq;
                }
            }
            acc2[nt] = __builtin_amdgcn_mfma_f32_16x16x32_bf16(ah, bh, acc2[nt], 0, 0, 0);
            acc2[nt] = __builtin_amdgcn_mfma_f32_16x16x32_bf16(ah, bl, acc2[nt], 0, 0, 0);
            acc2[nt] = __builtin_amdgcn_mfma_f32_16x16x32_bf16(al, bh, acc2[nt], 0, 0, 0);
        }
    }
    __syncthreads();

    float* os = (float*)(smem + 13056);
    #pragma unroll
    for (int nt = 0; nt < 2; ++nt) {
        const int c = ((w << 1) + nt) * 16 + nib;
        const float bb = b2[c];
        #pragma unroll
        for (int reg = 0; reg < 4; ++reg) {
            const int r = quad * 4 + reg;
            os[r * 132 + c] = acc2[nt][reg] + bb;
        }
    }
    __syncthreads();

    {
        const int r = t >> 4, c = (t & 15) * 8;
        float4 o0 = *(float4*)&os[r * 132 + c];
        float4 o1 = *(float4*)&os[r * 132 + c + 4];
        const float4 p0 = *(const float4*)&xs[r * 204 + c];
        const float4 p1 = *(const float4*)&xs[r * 204 + c + 4];
        o0.x += p0.x; o0.y += p0.y; o0.z += p0.z; o0.w += p0.w;
        o1.x += p1.x; o1.y += p1.y; o1.z += p1.z; o1.w += p1.w;
        float* dst = bbase + (size_t)(1 + (d << 9) + n0 + r) * HID + c;
        *(float4*)dst = o0;
        *(float4*)(dst + 4) = o1;
    }
}

// ============================ LAUNCHER ============================

extern "C" void kernel_launch(void* const* d_in, const int* in_sizes, int n_in,
                              void* d_out, int out_size, void* d_ws, size_t ws_size,
                              hipStream_t stream) {
    const float* embedding  = (const float*)d_in[0];
    const float* emb_table  = (const float*)d_in[1];
    const float* W1         = (const float*)d_in[2];
    const float* b1         = (const float*)d_in[3];
    const float* W2         = (const float*)d_in[4];
    const float* b2         = (const float*)d_in[5];
    const int*   parent_idx = (const int*)d_in[6];
    float* out = (float*)d_out;

    if (ws_size >= FW_BYTES) {
        char* ws = (char*)d_ws;
        init_fast_kernel<<<16, 256, 0, stream>>>(embedding, out, (float*)(ws + FW_WB));
        prep_w_fast<<<64, 256, 0, stream>>>(W1, W2, ws);
        prep_e_fast<<<1024, 256, 0, stream>>>(emb_table, W1, b1, (float*)(ws + FW_EP));
        for (int d = 0; d < DEPTHS; ++d) {
            depth_fast_kernel<<<1024, 256, 0, stream>>>(out, parent_idx, b2, ws, d);
        }
    } else {
        unsigned short* wsw = (unsigned short*)d_ws;
        const int use_ws = (ws_size >= (size_t)WS_BYTES) ? 1 : 0;
        init_kernel<<<16, 256, 0, stream>>>(embedding, out);
        if (use_ws) prep_kernel<<<160, 256, 0, stream>>>(W1, W2, wsw);
        for (int d = 0; d < DEPTHS; ++d) {
            depth_kernel<<<1024, 256, 0, stream>>>(out, emb_table, W1, b1, W2, b2,
                                                   parent_idx, wsw, d, use_ws);
        }
    }
}